// Round 15
// baseline (1514.481 us; speedup 1.0000x reference)
//
#include <hip/hip_runtime.h>
#include <hip/hip_bf16.h>
#include <stdint.h>

typedef __bf16 bf16_t;
typedef bf16_t bf16x8 __attribute__((ext_vector_type(8)));
typedef bf16_t bf16x4 __attribute__((ext_vector_type(4)));
typedef float  f32x4  __attribute__((ext_vector_type(4)));

#define AS1 __attribute__((address_space(1)))
#define AS3 __attribute__((address_space(3)))

#define WAITV(n) asm volatile("s_waitcnt vmcnt(" #n ")" ::: "memory")
#define SBAR() asm volatile("s_barrier" ::: "memory")

__device__ __forceinline__ void gload_lds16(const void* g, void* l) {
  __builtin_amdgcn_global_load_lds((const AS1 void*)g, (AS3 void*)l, 16, 0, 0);
}

// v_exp_f32 (2^x). Measured faster than any full-rate polynomial (r9 A/B).
__device__ __forceinline__ float fast_exp2(float x) {
#if __has_builtin(__builtin_amdgcn_exp2f)
  return __builtin_amdgcn_exp2f(x);
#else
  return exp2f(x);
#endif
}

// log2(e) / sqrt(64): folded into the wq weights so attention runs in exp2 domain.
#define QSCALE 0.1803368801111204f

// ---------------------------------------------------------------- GEMM
// C = A[M,K](bf16 rm) * B, with B as Bt[N,K] bf16. 128x128 tile, BK=64,
// 256 thr (4 waves), XOR-swizzled LDS, XCD-chunked block swizzle.
// Used for QKV (N=1536 fused, routes to 3 buffers) and FFN1 (relu+bias):
// single-buffer, latency hidden by 5 blocks/CU TLP.
template <int RELU, int BIAS, int QKV, int DBUF>
__global__ __launch_bounds__(256) void gemm_bt(const bf16_t* __restrict__ A,
                                               const bf16_t* __restrict__ Bt,
                                               const float* __restrict__ bias,
                                               bf16_t* __restrict__ Cv,
                                               int M, int N, int K, int ldc) {
  __shared__ __align__(16) char smem[DBUF ? 65536 : 32768];
  const int t = threadIdx.x;
  const int l = t & 63;
  const int w = t >> 6;
  const int wm = w >> 1, wn = w & 1;
  const int lr = l & 15, lg = l >> 4;

  const int gx = gridDim.x;
  const int nwg = gx * gridDim.y;
  const int orig = blockIdx.y * gx + blockIdx.x;
  const int swz = (orig & 7) * (nwg >> 3) + (orig >> 3);
  const long m0 = (long)(swz / gx) * 128;
  const long n0 = (long)(swz % gx) * 128;

  const bf16_t* asrc[4];
  const bf16_t* bsrc[4];
#pragma unroll
  for (int it = 0; it < 4; ++it) {
    int y = it * 4096 + t * 16;
    int row = y >> 7;
    int col = ((y & 127) ^ ((row & 7) << 4)) >> 1;
    asrc[it] = A + (m0 + row) * (long)K + col;
    bsrc[it] = Bt + (n0 + row) * (long)K + col;
  }

  auto stage = [&](int buf) {
    char* sb = smem + buf * 32768;
#pragma unroll
    for (int it = 0; it < 4; ++it) {
      gload_lds16(asrc[it], sb + it * 4096 + t * 16);
      gload_lds16(bsrc[it], sb + 16384 + it * 4096 + t * 16);
      asrc[it] += 64;
      bsrc[it] += 64;
    }
  };

  f32x4 acc[4][4] = {};
  const int nt = K >> 6;

  auto compute = [&](char* sb) {
#pragma unroll
    for (int kk = 0; kk < 2; ++kk) {
      const int c2 = (kk * 32 + lg * 8) * 2;
      bf16x8 a[4], b[4];
#pragma unroll
      for (int i = 0; i < 4; ++i) {
        int ra = wm * 64 + i * 16 + lr;
        a[i] = *(const bf16x8*)(sb + ((ra * 128 + c2) ^ ((ra & 7) << 4)));
        int rb = wn * 64 + i * 16 + lr;
        b[i] = *(const bf16x8*)(sb + 16384 + ((rb * 128 + c2) ^ ((rb & 7) << 4)));
      }
      __builtin_amdgcn_s_setprio(1);
#pragma unroll
      for (int i = 0; i < 4; ++i)
#pragma unroll
        for (int j = 0; j < 4; ++j)
          acc[i][j] = __builtin_amdgcn_mfma_f32_16x16x32_bf16(a[i], b[j], acc[i][j], 0, 0, 0);
      __builtin_amdgcn_s_setprio(0);
    }
  };

  if (DBUF) {
    stage(0);
    __syncthreads();
    int buf = 0;
    for (int kt = 0; kt < nt; ++kt) {
      if (kt + 1 < nt) stage(buf ^ 1);
      compute(smem + buf * 32768);
      __syncthreads();
      buf ^= 1;
    }
  } else {
    for (int kt = 0; kt < nt; ++kt) {
      __syncthreads();
      stage(0);
      __syncthreads();
      compute(smem);
    }
  }

  float bv[4];
  if (BIAS) {
#pragma unroll
    for (int j = 0; j < 4; ++j) bv[j] = bias[n0 + wn * 64 + j * 16 + lr];
  }
#pragma unroll
  for (int i = 0; i < 4; ++i) {
    long rowb = m0 + wm * 64 + i * 16 + lg * 4;
#pragma unroll
    for (int j = 0; j < 4; ++j) {
      int colbase = (int)n0 + wn * 64 + j * 16;
      bf16_t* outp;
      int coll;
      if (QKV) {
        outp = Cv + (size_t)(colbase >> 9) * 8388608;  // part * M*512
        coll = (colbase & 511) + lr;
      } else {
        outp = Cv;
        coll = colbase + lr;
      }
#pragma unroll
      for (int r = 0; r < 4; ++r) {
        float v = acc[i][j][r];
        if (BIAS) v += bv[j];
        if (RELU) v = v > 0.f ? v : 0.f;
        outp[(rowb + r) * (long)ldc + coll] = (bf16_t)v;
      }
    }
  }
}

// ---------------------------------------------------------------- GEMM + residual + LN
// delta = A[M,K] @ Bt[512,K]^T (+bias); x = LN(x + delta) fused in-epilogue.
// Tile 64 rows x 512 cols (FULL rows -> block-local LayerNorm), BK=64, 8 waves.
// SINGLE-buffer 72KB LDS -> 2 blocks/CU: sibling-block TLP covers the staging
// drain (the r11 144KB dbuf had 1 block/CU and the syncthreads drained the
// prefetch anyway). FINAL=1 also writes fp32 output.
template <int BIAS, int FINAL>
__global__ __launch_bounds__(512) void gemm_resln(const bf16_t* __restrict__ A,
                                                  const bf16_t* __restrict__ Bt,
                                                  const float* __restrict__ bias,
                                                  bf16_t* __restrict__ xb,
                                                  float* __restrict__ xout,
                                                  const float* __restrict__ g,
                                                  const float* __restrict__ be,
                                                  int K) {
  __shared__ __align__(16) char smem[73728];  // {A 8K, B 64K}
  const int t = threadIdx.x, l = t & 63, w = t >> 6;  // w = col-wave 0..7
  const int lr = l & 15, lg = l >> 4;
  const int orig = blockIdx.x;
  const int swz = (orig & 7) * 32 + (orig >> 3);  // 256 blocks, bijective
  const long m0 = (long)swz * 64;

  const bf16_t* src[9];
#pragma unroll
  for (int i = 0; i < 9; ++i) {
    int gy = i * 8192 + t * 16;
    if (gy < 8192) {
      int row = gy >> 7;
      int col = ((gy & 127) ^ ((row & 7) << 4)) >> 1;
      src[i] = A + (m0 + row) * (long)K + col;
    } else {
      int by = gy - 8192;
      int row = by >> 7;
      int col = ((by & 127) ^ ((row & 7) << 4)) >> 1;
      src[i] = Bt + (long)row * K + col;
    }
  }
  auto stage = [&]() {
#pragma unroll
    for (int i = 0; i < 9; ++i) {
      gload_lds16(src[i], smem + i * 8192 + t * 16);
      src[i] += 64;
    }
  };

  f32x4 acc[4][4] = {};
  const int nt = K >> 6;
  for (int kt = 0; kt < nt; ++kt) {
    __syncthreads();  // prior compute's LDS reads done
    stage();
    __syncthreads();  // tile resident
#pragma unroll
    for (int kk = 0; kk < 2; ++kk) {
      const int c2 = (kk * 32 + lg * 8) * 2;
      bf16x8 a[4], b[4];
#pragma unroll
      for (int i = 0; i < 4; ++i) {
        int ra = i * 16 + lr;
        a[i] = *(const bf16x8*)(smem + ((ra * 128 + c2) ^ ((ra & 7) << 4)));
        int rb = w * 64 + i * 16 + lr;
        b[i] = *(const bf16x8*)(smem + 8192 + ((rb * 128 + c2) ^ ((rb & 7) << 4)));
      }
      __builtin_amdgcn_s_setprio(1);
#pragma unroll
      for (int i = 0; i < 4; ++i)
#pragma unroll
        for (int j = 0; j < 4; ++j)
          acc[i][j] = __builtin_amdgcn_mfma_f32_16x16x32_bf16(a[i], b[j], acc[i][j], 0, 0, 0);
      __builtin_amdgcn_s_setprio(0);
    }
  }

  float* lnsum = (float*)smem;            // [64][8]
  float* lnsq  = (float*)(smem + 2048);   // [64][8]
  float* lnm   = (float*)(smem + 4096);   // [64]
  float* lnr   = (float*)(smem + 4352);   // [64]

  float bv[4];
  if (BIAS) {
#pragma unroll
    for (int j = 0; j < 4; ++j) bv[j] = bias[w * 64 + j * 16 + lr];
  }
  float sv[4][4][4];  // [mf][r][nj]
#pragma unroll
  for (int i = 0; i < 4; ++i)
#pragma unroll
    for (int r = 0; r < 4; ++r) {
      long row = m0 + i * 16 + lg * 4 + r;
#pragma unroll
      for (int j = 0; j < 4; ++j) {
        float d = acc[i][j][r];
        if (BIAS) d += bv[j];
        float xold = (float)xb[row * 512 + w * 64 + j * 16 + lr];
        sv[i][r][j] = xold + d;
      }
    }
  __syncthreads();  // final tile's LDS reads done; safe to reuse for LN reduce
#pragma unroll
  for (int i = 0; i < 4; ++i)
#pragma unroll
    for (int r = 0; r < 4; ++r) {
      float ps = sv[i][r][0] + sv[i][r][1] + sv[i][r][2] + sv[i][r][3];
      float pq = sv[i][r][0] * sv[i][r][0] + sv[i][r][1] * sv[i][r][1] +
                 sv[i][r][2] * sv[i][r][2] + sv[i][r][3] * sv[i][r][3];
#pragma unroll
      for (int m = 1; m <= 8; m <<= 1) {
        ps += __shfl_xor(ps, m, 64);
        pq += __shfl_xor(pq, m, 64);
      }
      if (lr == 0) {
        int rl = i * 16 + lg * 4 + r;
        lnsum[rl * 8 + w] = ps;
        lnsq[rl * 8 + w] = pq;
      }
    }
  __syncthreads();
  if (t < 64) {
    float s8 = 0.f, q8 = 0.f;
#pragma unroll
    for (int wv = 0; wv < 8; ++wv) {
      s8 += lnsum[t * 8 + wv];
      q8 += lnsq[t * 8 + wv];
    }
    float mu = s8 * (1.f / 512.f);
    float var = q8 * (1.f / 512.f) - mu * mu;
    lnm[t] = mu;
    lnr[t] = rsqrtf(var + 1e-5f);
  }
  __syncthreads();
  float gv[4], bev[4];
#pragma unroll
  for (int j = 0; j < 4; ++j) {
    gv[j] = g[w * 64 + j * 16 + lr];
    bev[j] = be[w * 64 + j * 16 + lr];
  }
#pragma unroll
  for (int i = 0; i < 4; ++i)
#pragma unroll
    for (int r = 0; r < 4; ++r) {
      int rl = i * 16 + lg * 4 + r;
      long row = m0 + rl;
      float mu = lnm[rl], rstd = lnr[rl];
#pragma unroll
      for (int j = 0; j < 4; ++j) {
        int col = w * 64 + j * 16 + lr;
        float y = (sv[i][r][j] - mu) * rstd * gv[j] + bev[j];
        xb[row * 512 + col] = (bf16_t)y;
        if (FINAL) xout[row * 512 + col] = y;
      }
    }
}

// ---------------------------------------------------------------- Attention
// 64 head-problems, each contiguous (2048,64) bf16. Grid 512 (64 heads x 8
// q-tiles), head-clustered XCD swizzle. 512 thr = 8 waves, QBLK=256 (32 rows
// per wave), KVBLK=64, swapped QK^T, P in registers (sigma-permuted PV),
// V via ds_read_b64_tr_b16, max-free exp2-domain softmax, row-sum via
// ones-MFMA. 5-buffer pipeline, 2 tiles per barrier with SPLIT waits.
__global__ __launch_bounds__(512) void attn_fa(const bf16_t* __restrict__ qg,
                                               const bf16_t* __restrict__ kg,
                                               const bf16_t* __restrict__ vg,
                                               bf16_t* __restrict__ og) {
  __shared__ __align__(16) char smem[81920];  // 5 x {K 8K, Vsub 8K}
  const int t = threadIdx.x, l = t & 63, w = t >> 6;  // w = q-wave 0..7
  const int lr = l & 15, lg = l >> 4;
  const int lin = blockIdx.x;
  const int swz = (lin & 7) * 64 + (lin >> 3);
  const long hoff = (long)(swz >> 3) * 131072;
  const int q0 = (swz & 7) * 256 + w * 32;
  const uint32_t LDSB = (uint32_t)(uintptr_t)(AS3 char*)smem;

  bf16x8 qf[2][2];
#pragma unroll
  for (int nf = 0; nf < 2; ++nf)
#pragma unroll
    for (int kk = 0; kk < 2; ++kk)
      qf[nf][kk] = *(const bf16x8*)(qg + hoff + (long)(q0 + nf * 16 + lr) * 64 + kk * 32 + lg * 8);

  const bf16_t* ksrc;
  {
    int y = t * 16;
    int row = y >> 7;
    int col = ((y & 127) ^ ((row & 7) << 4)) >> 1;
    ksrc = kg + hoff + (long)row * 64 + col;
  }
  const bf16_t* vsrc;
  {
    int y = t * 16;
    int kk = y >> 12;
    int nj = (y >> 10) & 3;
    int jhi = (y >> 9) & 1;
    int lgs = (y >> 7) & 3;
    int r = (y >> 5) & 3;
    int ch = (y >> 4) & 1;
    int kv = kk * 32 + jhi * 16 + lgs * 4 + r;
    int d0 = nj * 16 + ch * 8;
    vsrc = vg + hoff + (long)kv * 64 + d0;
  }

  auto stage = [&](int buf) {
    char* sb = smem + buf * 16384;
    gload_lds16(ksrc, sb + t * 16);
    gload_lds16(vsrc, sb + 8192 + t * 16);
    ksrc += 4096;
    vsrc += 4096;
  };

  f32x4 oacc[2][4] = {};
  f32x4 lacc[2] = {};
  bf16x8 onesf;
#pragma unroll
  for (int j = 0; j < 8; ++j) onesf[j] = (bf16_t)1.0f;

  auto tile_compute = [&](int bufIdx) {
    char* sb = smem + bufIdx * 16384;
    // S^T = K * Q^T : lane (lr,lg) gets S[kv=16mf+4lg+r][q=nf*16+lr]
    f32x4 sT[4][2] = {};
#pragma unroll
    for (int kk = 0; kk < 2; ++kk) {
      const int c2 = (kk * 32 + lg * 8) * 2;
      bf16x8 kf[4];
#pragma unroll
      for (int mf = 0; mf < 4; ++mf) {
        int rk = mf * 16 + lr;
        kf[mf] = *(const bf16x8*)(sb + ((rk * 128 + c2) ^ ((rk & 7) << 4)));
      }
      __builtin_amdgcn_s_setprio(1);
#pragma unroll
      for (int mf = 0; mf < 4; ++mf)
#pragma unroll
        for (int nf = 0; nf < 2; ++nf)
          sT[mf][nf] = __builtin_amdgcn_mfma_f32_16x16x32_bf16(kf[mf], qf[nf][kk], sT[mf][nf], 0, 0, 0);
      __builtin_amdgcn_s_setprio(0);
    }

    // issue ALL 16 V transpose-reads; latency hides under the softmax VALU
    uint32_t va = LDSB + (uint32_t)bufIdx * 16384u + 8192u + (uint32_t)l * 8u;
    bf16x4 tv0, tv1, tv2, tv3, tv4, tv5, tv6, tv7;
    bf16x4 tv8, tv9, tva, tvb, tvc, tvd, tve, tvf;
    asm volatile(
        "ds_read_b64_tr_b16 %0, %16 offset:0\n\t"
        "ds_read_b64_tr_b16 %1, %16 offset:512\n\t"
        "ds_read_b64_tr_b16 %2, %16 offset:1024\n\t"
        "ds_read_b64_tr_b16 %3, %16 offset:1536\n\t"
        "ds_read_b64_tr_b16 %4, %16 offset:2048\n\t"
        "ds_read_b64_tr_b16 %5, %16 offset:2560\n\t"
        "ds_read_b64_tr_b16 %6, %16 offset:3072\n\t"
        "ds_read_b64_tr_b16 %7, %16 offset:3584\n\t"
        "ds_read_b64_tr_b16 %8, %16 offset:4096\n\t"
        "ds_read_b64_tr_b16 %9, %16 offset:4608\n\t"
        "ds_read_b64_tr_b16 %10, %16 offset:5120\n\t"
        "ds_read_b64_tr_b16 %11, %16 offset:5632\n\t"
        "ds_read_b64_tr_b16 %12, %16 offset:6144\n\t"
        "ds_read_b64_tr_b16 %13, %16 offset:6656\n\t"
        "ds_read_b64_tr_b16 %14, %16 offset:7168\n\t"
        "ds_read_b64_tr_b16 %15, %16 offset:7680"
        : "=&v"(tv0), "=&v"(tv1), "=&v"(tv2), "=&v"(tv3),
          "=&v"(tv4), "=&v"(tv5), "=&v"(tv6), "=&v"(tv7),
          "=&v"(tv8), "=&v"(tv9), "=&v"(tva), "=&v"(tvb),
          "=&v"(tvc), "=&v"(tvd), "=&v"(tve), "=&v"(tvf)
        : "v"(va));

    // P = exp2(S) (max-free), packed as PV A-fragments (sigma order)
    bf16x8 pa[2][2];
#pragma unroll
    for (int m2 = 0; m2 < 2; ++m2)
#pragma unroll
      for (int kk = 0; kk < 2; ++kk) {
        f32x4 e0, e1;
#pragma unroll
        for (int r = 0; r < 4; ++r) {
          e0[r] = fast_exp2(sT[2 * kk][m2][r]);
          e1[r] = fast_exp2(sT[2 * kk + 1][m2][r]);
        }
        bf16x4 c0 = __builtin_convertvector(e0, bf16x4);
        bf16x4 c1 = __builtin_convertvector(e1, bf16x4);
        pa[m2][kk] = __builtin_shufflevector(c0, c1, 0, 1, 2, 3, 4, 5, 6, 7);
      }

    asm volatile("s_waitcnt lgkmcnt(0)" ::: "memory");
    __builtin_amdgcn_sched_barrier(0);

    bf16x8 vf[2][4];
    vf[0][0] = __builtin_shufflevector(tv0, tv1, 0, 1, 2, 3, 4, 5, 6, 7);
    vf[0][1] = __builtin_shufflevector(tv2, tv3, 0, 1, 2, 3, 4, 5, 6, 7);
    vf[0][2] = __builtin_shufflevector(tv4, tv5, 0, 1, 2, 3, 4, 5, 6, 7);
    vf[0][3] = __builtin_shufflevector(tv6, tv7, 0, 1, 2, 3, 4, 5, 6, 7);
    vf[1][0] = __builtin_shufflevector(tv8, tv9, 0, 1, 2, 3, 4, 5, 6, 7);
    vf[1][1] = __builtin_shufflevector(tva, tvb, 0, 1, 2, 3, 4, 5, 6, 7);
    vf[1][2] = __builtin_shufflevector(tvc, tvd, 0, 1, 2, 3, 4, 5, 6, 7);
    vf[1][3] = __builtin_shufflevector(tve, tvf, 0, 1, 2, 3, 4, 5, 6, 7);

    __builtin_amdgcn_s_setprio(1);
#pragma unroll
    for (int kk = 0; kk < 2; ++kk)
#pragma unroll
      for (int m2 = 0; m2 < 2; ++m2) {
#pragma unroll
        for (int nj = 0; nj < 4; ++nj)
          oacc[m2][nj] = __builtin_amdgcn_mfma_f32_16x16x32_bf16(pa[m2][kk], vf[kk][nj], oacc[m2][nj], 0, 0, 0);
        lacc[m2] = __builtin_amdgcn_mfma_f32_16x16x32_bf16(pa[m2][kk], onesf, lacc[m2], 0, 0, 0);
      }
    __builtin_amdgcn_s_setprio(0);
  };

  // prologue: tiles 0,1,2 staged (6 loads in flight)
  stage(0);
  stage(1);
  stage(2);
  int nxt = 3;
  // steady state i=0..13: entry outstanding = {2i,2i+1,2i+2} (6 loads)
  for (int i = 0; i < 14; ++i) {
    WAITV(4);            // tile 2i resident (all but newest 2 groups)
    SBAR();
    stage(nxt % 5); ++nxt;
    stage(nxt % 5); ++nxt;
    tile_compute((2 * i) % 5);
    WAITV(6);            // tile 2i+1 resident (newest 3 groups may remain)
    tile_compute((2 * i + 1) % 5);
  }
  // i=14: entry {28,29,30}; stage 31 only
  WAITV(4);
  SBAR();
  stage(31 % 5);
  tile_compute(28 % 5);
  WAITV(4);              // tile 29 resident (30,31 may remain)
  tile_compute(29 % 5);
  // i=15: entry {30,31}
  WAITV(2);
  SBAR();
  tile_compute(30 % 5);
  WAITV(0);
  tile_compute(31 % 5);

#pragma unroll
  for (int m2 = 0; m2 < 2; ++m2)
#pragma unroll
    for (int r = 0; r < 4; ++r) {
      float inv = 1.f / lacc[m2][r];
      long row = q0 + m2 * 16 + lg * 4 + r;
#pragma unroll
      for (int nj = 0; nj < 4; ++nj)
        og[hoff + row * 64 + nj * 16 + lr] = (bf16_t)(oacc[m2][nj][r] * inv);
    }
}

// ---------------------------------------------------------------- transpose+cvt
// Generic (for w1/w2): src fp32 (K,N) layer z -> dst bf16 (N,K), scaled.
__global__ __launch_bounds__(256) void transpose_w(const float* __restrict__ src,
                                                   bf16_t* __restrict__ dst,
                                                   int K, int N,
                                                   long dstLayerStride, float scale) {
  __shared__ float tile[32][33];
  const int t = threadIdx.x;
  const int tx = t & 31, ty = t >> 5;
  const long ls = (long)blockIdx.z * K * N;
  const long ld = (long)blockIdx.z * dstLayerStride;
  const int n0 = blockIdx.x * 32, k0 = blockIdx.y * 32;
#pragma unroll
  for (int i = 0; i < 4; ++i)
    tile[ty + i * 8][tx] = src[ls + (long)(k0 + ty + i * 8) * N + n0 + tx];
  __syncthreads();
#pragma unroll
  for (int i = 0; i < 4; ++i)
    dst[ld + (long)(n0 + ty + i * 8) * K + k0 + tx] = (bf16_t)(tile[tx][ty + i * 8] * scale);
}

// Fused 512x512 transposes: z in [0,24): layer L=z>>2, which=z&3
// which 0..2 -> wq/wk/wv into wqkvt parts (wq scaled by QSCALE); 3 -> wo.
__global__ __launch_bounds__(256) void transpose_w4(const float* __restrict__ wq,
                                                    const float* __restrict__ wk,
                                                    const float* __restrict__ wv,
                                                    const float* __restrict__ wo,
                                                    bf16_t* __restrict__ wqkvt,
                                                    bf16_t* __restrict__ wot) {
  __shared__ float tile[32][33];
  const int t = threadIdx.x;
  const int tx = t & 31, ty = t >> 5;
  const int z = blockIdx.z, L = z >> 2, which = z & 3;
  const float* src;
  bf16_t* dst;
  float scale = 1.f;
  const long LQKV = 1536L * 512;
  if (which == 0) { src = wq; dst = wqkvt + (long)L * LQKV; scale = QSCALE; }
  else if (which == 1) { src = wk; dst = wqkvt + (long)L * LQKV + 512 * 512; }
  else if (which == 2) { src = wv; dst = wqkvt + (long)L * LQKV + 2 * 512 * 512; }
  else { src = wo; dst = wot + (long)L * 512 * 512; }
  src += (long)L * 512 * 512;
  const int n0 = blockIdx.x * 32, k0 = blockIdx.y * 32;
#pragma unroll
  for (int i = 0; i < 4; ++i)
    tile[ty + i * 8][tx] = src[(long)(k0 + ty + i * 8) * 512 + n0 + tx];
  __syncthreads();
#pragma unroll
  for (int i = 0; i < 4; ++i)
    dst[(long)(n0 + ty + i * 8) * 512 + k0 + tx] = (bf16_t)(tile[tx][ty + i * 8] * scale);
}

// ---------------------------------------------------------------- init
__global__ __launch_bounds__(256) void init_x(const float* __restrict__ x,
                                              bf16_t* __restrict__ xb) {
  long i = ((long)blockIdx.x * 256 + threadIdx.x) * 8;
  f32x4 a = *(const f32x4*)(x + i);
  f32x4 b = *(const f32x4*)(x + i + 4);
  bf16x8 o;
#pragma unroll
  for (int j = 0; j < 4; ++j) { o[j] = (bf16_t)a[j]; o[4 + j] = (bf16_t)b[j]; }
  *(bf16x8*)(xb + i) = o;
}

// ---------------------------------------------------------------- launch
extern "C" void kernel_launch(void* const* d_in, const int* in_sizes, int n_in,
                              void* d_out, int out_size, void* d_ws, size_t ws_size,
                              hipStream_t stream) {
  const float* x = (const float*)d_in[0];
  const float* wq = (const float*)d_in[1];
  const float* wk = (const float*)d_in[2];
  const float* wv = (const float*)d_in[3];
  const float* wo = (const float*)d_in[4];
  const float* w1 = (const float*)d_in[5];
  const float* b1 = (const float*)d_in[6];
  const float* w2 = (const float*)d_in[7];
  const float* b2 = (const float*)d_in[8];
  const float* g1 = (const float*)d_in[9];
  const float* be1 = (const float*)d_in[10];
  const float* g2 = (const float*)d_in[11];
  const float* be2 = (const float*)d_in[12];

  char* ws = (char*)d_ws;

  const int M = 16384, D = 512, DFF = 2048, NL = 6;
  const size_t sz_small = (size_t)NL * D * D * 2;
  const size_t sz_big = (size_t)NL * D * DFF * 2;
  bf16_t* wqkvt = (bf16_t*)(ws);                       // [NL][1536][512]
  bf16_t* wot = (bf16_t*)(ws + 3 * sz_small);
  bf16_t* w1t = (bf16_t*)(ws + 4 * sz_small);
  bf16_t* w2t = (bf16_t*)(ws + 4 * sz_small + sz_big);
  char* actbase = ws + 4 * sz_small + 2 * sz_big;
  bf16_t* xb = (bf16_t*)(actbase);                         // bf16 residual master
  char* R = actbase + (size_t)M * D * 2;
  bf16_t* qb = (bf16_t*)(R);
  bf16_t* kb = (bf16_t*)(R + (size_t)M * D * 2);
  bf16_t* vb = (bf16_t*)(R + 2 * (size_t)M * D * 2);
  bf16_t* ob = (bf16_t*)(R + 3 * (size_t)M * D * 2);
  bf16_t* hb = (bf16_t*)(R);                               // FFN hidden reuses R

  const long LQKV = 1536L * 512;
  transpose_w4<<<dim3(16, 16, 24), 256, 0, stream>>>(wq, wk, wv, wo, wqkvt, wot);
  transpose_w<<<dim3(DFF / 32, D / 32, NL), 256, 0, stream>>>(w1, w1t, D, DFF, (long)D * DFF, 1.f);
  transpose_w<<<dim3(D / 32, DFF / 32, NL), 256, 0, stream>>>(w2, w2t, DFF, D, (long)D * DFF, 1.f);
  init_x<<<4096, 256, 0, stream>>>(x, xb);

  for (int L = 0; L < NL; ++L) {
    const bf16_t* wqkvL = wqkvt + (size_t)L * LQKV;
    const bf16_t* w1L = w1t + (size_t)L * D * DFF;
    const bf16_t* w2L = w2t + (size_t)L * D * DFF;
    const bf16_t* woL = wot + (size_t)L * D * D;

    gemm_bt<0, 0, 1, 0><<<dim3(12, 128), 256, 0, stream>>>(xb, wqkvL, nullptr, qb, M, 1536, D, 512);
    attn_fa<<<dim3(512), 512, 0, stream>>>(qb, kb, vb, ob);
    gemm_resln<0, 0><<<dim3(256), 512, 0, stream>>>(ob, woL, nullptr, xb, nullptr,
                                                    g1 + L * D, be1 + L * D, D);
    gemm_bt<1, 1, 0, 0><<<dim3(16, 128), 256, 0, stream>>>(xb, w1L, b1 + (size_t)L * DFF, hb, M, DFF, D, DFF);
    if (L == NL - 1)
      gemm_resln<1, 1><<<dim3(256), 512, 0, stream>>>(hb, w2L, b2 + L * D, xb, (float*)d_out,
                                                      g2 + L * D, be2 + L * D, DFF);
    else
      gemm_resln<1, 0><<<dim3(256), 512, 0, stream>>>(hb, w2L, b2 + L * D, xb, nullptr,
                                                      g2 + L * D, be2 + L * D, DFF);
  }
}

// Round 16
// 1388.977 us; speedup vs baseline: 1.0904x; 1.0904x over previous
//
#include <hip/hip_runtime.h>
#include <hip/hip_bf16.h>
#include <stdint.h>

typedef __bf16 bf16_t;
typedef bf16_t bf16x8 __attribute__((ext_vector_type(8)));
typedef bf16_t bf16x4 __attribute__((ext_vector_type(4)));
typedef float  f32x4  __attribute__((ext_vector_type(4)));

#define AS1 __attribute__((address_space(1)))
#define AS3 __attribute__((address_space(3)))

#define WAITV(n) asm volatile("s_waitcnt vmcnt(" #n ")" ::: "memory")
#define SBAR() asm volatile("s_barrier" ::: "memory")

__device__ __forceinline__ void gload_lds16(const void* g, void* l) {
  __builtin_amdgcn_global_load_lds((const AS1 void*)g, (AS3 void*)l, 16, 0, 0);
}

// v_exp_f32 (2^x). Measured faster than any full-rate polynomial (r9 A/B).
__device__ __forceinline__ float fast_exp2(float x) {
#if __has_builtin(__builtin_amdgcn_exp2f)
  return __builtin_amdgcn_exp2f(x);
#else
  return exp2f(x);
#endif
}

// log2(e) / sqrt(64): folded into the wq weights so attention runs in exp2 domain.
#define QSCALE 0.1803368801111204f

// ---------------------------------------------------------------- GEMM
// C = A[M,K](bf16 rm) * B, with B as Bt[N,K] bf16. 128x128 tile, BK=64,
// 256 thr (4 waves), XOR-swizzled LDS, XCD-chunked block swizzle.
// Used for QKV (N=1536 fused, routes to 3 buffers) and FFN1 (relu+bias):
// single-buffer, latency hidden by 5 blocks/CU TLP.
template <int RELU, int BIAS, int QKV, int DBUF>
__global__ __launch_bounds__(256) void gemm_bt(const bf16_t* __restrict__ A,
                                               const bf16_t* __restrict__ Bt,
                                               const float* __restrict__ bias,
                                               bf16_t* __restrict__ Cv,
                                               int M, int N, int K, int ldc) {
  __shared__ __align__(16) char smem[DBUF ? 65536 : 32768];
  const int t = threadIdx.x;
  const int l = t & 63;
  const int w = t >> 6;
  const int wm = w >> 1, wn = w & 1;
  const int lr = l & 15, lg = l >> 4;

  const int gx = gridDim.x;
  const int nwg = gx * gridDim.y;
  const int orig = blockIdx.y * gx + blockIdx.x;
  const int swz = (orig & 7) * (nwg >> 3) + (orig >> 3);
  const long m0 = (long)(swz / gx) * 128;
  const long n0 = (long)(swz % gx) * 128;

  const bf16_t* asrc[4];
  const bf16_t* bsrc[4];
#pragma unroll
  for (int it = 0; it < 4; ++it) {
    int y = it * 4096 + t * 16;
    int row = y >> 7;
    int col = ((y & 127) ^ ((row & 7) << 4)) >> 1;
    asrc[it] = A + (m0 + row) * (long)K + col;
    bsrc[it] = Bt + (n0 + row) * (long)K + col;
  }

  auto stage = [&](int buf) {
    char* sb = smem + buf * 32768;
#pragma unroll
    for (int it = 0; it < 4; ++it) {
      gload_lds16(asrc[it], sb + it * 4096 + t * 16);
      gload_lds16(bsrc[it], sb + 16384 + it * 4096 + t * 16);
      asrc[it] += 64;
      bsrc[it] += 64;
    }
  };

  f32x4 acc[4][4] = {};
  const int nt = K >> 6;

  auto compute = [&](char* sb) {
#pragma unroll
    for (int kk = 0; kk < 2; ++kk) {
      const int c2 = (kk * 32 + lg * 8) * 2;
      bf16x8 a[4], b[4];
#pragma unroll
      for (int i = 0; i < 4; ++i) {
        int ra = wm * 64 + i * 16 + lr;
        a[i] = *(const bf16x8*)(sb + ((ra * 128 + c2) ^ ((ra & 7) << 4)));
        int rb = wn * 64 + i * 16 + lr;
        b[i] = *(const bf16x8*)(sb + 16384 + ((rb * 128 + c2) ^ ((rb & 7) << 4)));
      }
      __builtin_amdgcn_s_setprio(1);
#pragma unroll
      for (int i = 0; i < 4; ++i)
#pragma unroll
        for (int j = 0; j < 4; ++j)
          acc[i][j] = __builtin_amdgcn_mfma_f32_16x16x32_bf16(a[i], b[j], acc[i][j], 0, 0, 0);
      __builtin_amdgcn_s_setprio(0);
    }
  };

  if (DBUF) {
    stage(0);
    __syncthreads();
    int buf = 0;
    for (int kt = 0; kt < nt; ++kt) {
      if (kt + 1 < nt) stage(buf ^ 1);
      compute(smem + buf * 32768);
      __syncthreads();
      buf ^= 1;
    }
  } else {
    for (int kt = 0; kt < nt; ++kt) {
      __syncthreads();
      stage(0);
      __syncthreads();
      compute(smem);
    }
  }

  float bv[4];
  if (BIAS) {
#pragma unroll
    for (int j = 0; j < 4; ++j) bv[j] = bias[n0 + wn * 64 + j * 16 + lr];
  }
#pragma unroll
  for (int i = 0; i < 4; ++i) {
    long rowb = m0 + wm * 64 + i * 16 + lg * 4;
#pragma unroll
    for (int j = 0; j < 4; ++j) {
      int colbase = (int)n0 + wn * 64 + j * 16;
      bf16_t* outp;
      int coll;
      if (QKV) {
        outp = Cv + (size_t)(colbase >> 9) * 8388608;  // part * M*512
        coll = (colbase & 511) + lr;
      } else {
        outp = Cv;
        coll = colbase + lr;
      }
#pragma unroll
      for (int r = 0; r < 4; ++r) {
        float v = acc[i][j][r];
        if (BIAS) v += bv[j];
        if (RELU) v = v > 0.f ? v : 0.f;
        outp[(rowb + r) * (long)ldc + coll] = (bf16_t)v;
      }
    }
  }
}

// ---------------------------------------------------------------- GEMM + residual + LN
// delta = A[M,K] @ Bt[512,K]^T (+bias); x = LN(x + delta) fused in-epilogue.
// Tile 64 rows x 512 cols (FULL rows -> block-local LayerNorm), BK=64, 8 waves,
// double-buffered 144KB LDS, XCD swizzle. (r14-proven form; the r15
// single-buffer variant regressed +10us/dispatch.) FINAL=1 also writes fp32.
template <int BIAS, int FINAL>
__global__ __launch_bounds__(512) void gemm_resln(const bf16_t* __restrict__ A,
                                                  const bf16_t* __restrict__ Bt,
                                                  const float* __restrict__ bias,
                                                  bf16_t* __restrict__ xb,
                                                  float* __restrict__ xout,
                                                  const float* __restrict__ g,
                                                  const float* __restrict__ be,
                                                  int K) {
  __shared__ __align__(16) char smem[147456];  // 2 x {A 8K, B 64K}
  const int t = threadIdx.x, l = t & 63, w = t >> 6;  // w = col-wave 0..7
  const int lr = l & 15, lg = l >> 4;
  const int orig = blockIdx.x;
  const int swz = (orig & 7) * 32 + (orig >> 3);  // 256 blocks, bijective
  const long m0 = (long)swz * 64;

  const bf16_t* src[9];
#pragma unroll
  for (int i = 0; i < 9; ++i) {
    int gy = i * 8192 + t * 16;
    if (gy < 8192) {
      int row = gy >> 7;
      int col = ((gy & 127) ^ ((row & 7) << 4)) >> 1;
      src[i] = A + (m0 + row) * (long)K + col;
    } else {
      int by = gy - 8192;
      int row = by >> 7;
      int col = ((by & 127) ^ ((row & 7) << 4)) >> 1;
      src[i] = Bt + (long)row * K + col;
    }
  }
  auto stage = [&](int buf) {
    char* sb = smem + buf * 73728;
#pragma unroll
    for (int i = 0; i < 9; ++i) {
      gload_lds16(src[i], sb + i * 8192 + t * 16);
      src[i] += 64;
    }
  };

  f32x4 acc[4][4] = {};
  const int nt = K >> 6;
  stage(0);
  __syncthreads();
  int buf = 0;
  for (int kt = 0; kt < nt; ++kt) {
    if (kt + 1 < nt) stage(buf ^ 1);
    char* sb = smem + buf * 73728;
#pragma unroll
    for (int kk = 0; kk < 2; ++kk) {
      const int c2 = (kk * 32 + lg * 8) * 2;
      bf16x8 a[4], b[4];
#pragma unroll
      for (int i = 0; i < 4; ++i) {
        int ra = i * 16 + lr;
        a[i] = *(const bf16x8*)(sb + ((ra * 128 + c2) ^ ((ra & 7) << 4)));
        int rb = w * 64 + i * 16 + lr;
        b[i] = *(const bf16x8*)(sb + 8192 + ((rb * 128 + c2) ^ ((rb & 7) << 4)));
      }
      __builtin_amdgcn_s_setprio(1);
#pragma unroll
      for (int i = 0; i < 4; ++i)
#pragma unroll
        for (int j = 0; j < 4; ++j)
          acc[i][j] = __builtin_amdgcn_mfma_f32_16x16x32_bf16(a[i], b[j], acc[i][j], 0, 0, 0);
      __builtin_amdgcn_s_setprio(0);
    }
    __syncthreads();
    buf ^= 1;
  }

  float* lnsum = (float*)smem;            // [64][8]
  float* lnsq  = (float*)(smem + 2048);   // [64][8]
  float* lnm   = (float*)(smem + 4096);   // [64]
  float* lnr   = (float*)(smem + 4352);   // [64]

  float bv[4];
  if (BIAS) {
#pragma unroll
    for (int j = 0; j < 4; ++j) bv[j] = bias[w * 64 + j * 16 + lr];
  }
  float sv[4][4][4];  // [mf][r][nj]
#pragma unroll
  for (int i = 0; i < 4; ++i)
#pragma unroll
    for (int r = 0; r < 4; ++r) {
      long row = m0 + i * 16 + lg * 4 + r;
#pragma unroll
      for (int j = 0; j < 4; ++j) {
        float d = acc[i][j][r];
        if (BIAS) d += bv[j];
        float xold = (float)xb[row * 512 + w * 64 + j * 16 + lr];
        sv[i][r][j] = xold + d;
      }
    }
#pragma unroll
  for (int i = 0; i < 4; ++i)
#pragma unroll
    for (int r = 0; r < 4; ++r) {
      float ps = sv[i][r][0] + sv[i][r][1] + sv[i][r][2] + sv[i][r][3];
      float pq = sv[i][r][0] * sv[i][r][0] + sv[i][r][1] * sv[i][r][1] +
                 sv[i][r][2] * sv[i][r][2] + sv[i][r][3] * sv[i][r][3];
#pragma unroll
      for (int m = 1; m <= 8; m <<= 1) {
        ps += __shfl_xor(ps, m, 64);
        pq += __shfl_xor(pq, m, 64);
      }
      if (lr == 0) {
        int rl = i * 16 + lg * 4 + r;
        lnsum[rl * 8 + w] = ps;
        lnsq[rl * 8 + w] = pq;
      }
    }
  __syncthreads();
  if (t < 64) {
    float s8 = 0.f, q8 = 0.f;
#pragma unroll
    for (int wv = 0; wv < 8; ++wv) {
      s8 += lnsum[t * 8 + wv];
      q8 += lnsq[t * 8 + wv];
    }
    float mu = s8 * (1.f / 512.f);
    float var = q8 * (1.f / 512.f) - mu * mu;
    lnm[t] = mu;
    lnr[t] = rsqrtf(var + 1e-5f);
  }
  __syncthreads();
  float gv[4], bev[4];
#pragma unroll
  for (int j = 0; j < 4; ++j) {
    gv[j] = g[w * 64 + j * 16 + lr];
    bev[j] = be[w * 64 + j * 16 + lr];
  }
#pragma unroll
  for (int i = 0; i < 4; ++i)
#pragma unroll
    for (int r = 0; r < 4; ++r) {
      int rl = i * 16 + lg * 4 + r;
      long row = m0 + rl;
      float mu = lnm[rl], rstd = lnr[rl];
#pragma unroll
      for (int j = 0; j < 4; ++j) {
        int col = w * 64 + j * 16 + lr;
        float y = (sv[i][r][j] - mu) * rstd * gv[j] + bev[j];
        xb[row * 512 + col] = (bf16_t)y;
        if (FINAL) xout[row * 512 + col] = y;
      }
    }
}

// ---------------------------------------------------------------- Attention
// 64 head-problems, each contiguous (2048,64) bf16. Grid 512 (64 heads x 8
// q-tiles), head-clustered XCD swizzle. 512 thr = 8 waves, QBLK=256 (32 rows
// per wave), KVBLK=64, swapped QK^T, P in registers (sigma-permuted PV),
// V via ds_read_b64_tr_b16, max-free exp2-domain softmax, row-sum via
// ones-MFMA. 5-buffer pipeline, 2 tiles per barrier with SPLIT waits.
__global__ __launch_bounds__(512) void attn_fa(const bf16_t* __restrict__ qg,
                                               const bf16_t* __restrict__ kg,
                                               const bf16_t* __restrict__ vg,
                                               bf16_t* __restrict__ og) {
  __shared__ __align__(16) char smem[81920];  // 5 x {K 8K, Vsub 8K}
  const int t = threadIdx.x, l = t & 63, w = t >> 6;  // w = q-wave 0..7
  const int lr = l & 15, lg = l >> 4;
  const int lin = blockIdx.x;
  const int swz = (lin & 7) * 64 + (lin >> 3);
  const long hoff = (long)(swz >> 3) * 131072;
  const int q0 = (swz & 7) * 256 + w * 32;
  const uint32_t LDSB = (uint32_t)(uintptr_t)(AS3 char*)smem;

  bf16x8 qf[2][2];
#pragma unroll
  for (int nf = 0; nf < 2; ++nf)
#pragma unroll
    for (int kk = 0; kk < 2; ++kk)
      qf[nf][kk] = *(const bf16x8*)(qg + hoff + (long)(q0 + nf * 16 + lr) * 64 + kk * 32 + lg * 8);

  const bf16_t* ksrc;
  {
    int y = t * 16;
    int row = y >> 7;
    int col = ((y & 127) ^ ((row & 7) << 4)) >> 1;
    ksrc = kg + hoff + (long)row * 64 + col;
  }
  const bf16_t* vsrc;
  {
    int y = t * 16;
    int kk = y >> 12;
    int nj = (y >> 10) & 3;
    int jhi = (y >> 9) & 1;
    int lgs = (y >> 7) & 3;
    int r = (y >> 5) & 3;
    int ch = (y >> 4) & 1;
    int kv = kk * 32 + jhi * 16 + lgs * 4 + r;
    int d0 = nj * 16 + ch * 8;
    vsrc = vg + hoff + (long)kv * 64 + d0;
  }

  auto stage = [&](int buf) {
    char* sb = smem + buf * 16384;
    gload_lds16(ksrc, sb + t * 16);
    gload_lds16(vsrc, sb + 8192 + t * 16);
    ksrc += 4096;
    vsrc += 4096;
  };

  f32x4 oacc[2][4] = {};
  f32x4 lacc[2] = {};
  bf16x8 onesf;
#pragma unroll
  for (int j = 0; j < 8; ++j) onesf[j] = (bf16_t)1.0f;

  auto tile_compute = [&](int bufIdx) {
    char* sb = smem + bufIdx * 16384;
    // S^T = K * Q^T : lane (lr,lg) gets S[kv=16mf+4lg+r][q=nf*16+lr]
    f32x4 sT[4][2] = {};
#pragma unroll
    for (int kk = 0; kk < 2; ++kk) {
      const int c2 = (kk * 32 + lg * 8) * 2;
      bf16x8 kf[4];
#pragma unroll
      for (int mf = 0; mf < 4; ++mf) {
        int rk = mf * 16 + lr;
        kf[mf] = *(const bf16x8*)(sb + ((rk * 128 + c2) ^ ((rk & 7) << 4)));
      }
      __builtin_amdgcn_s_setprio(1);
#pragma unroll
      for (int mf = 0; mf < 4; ++mf)
#pragma unroll
        for (int nf = 0; nf < 2; ++nf)
          sT[mf][nf] = __builtin_amdgcn_mfma_f32_16x16x32_bf16(kf[mf], qf[nf][kk], sT[mf][nf], 0, 0, 0);
      __builtin_amdgcn_s_setprio(0);
    }

    // issue ALL 16 V transpose-reads; latency hides under the softmax VALU
    uint32_t va = LDSB + (uint32_t)bufIdx * 16384u + 8192u + (uint32_t)l * 8u;
    bf16x4 tv0, tv1, tv2, tv3, tv4, tv5, tv6, tv7;
    bf16x4 tv8, tv9, tva, tvb, tvc, tvd, tve, tvf;
    asm volatile(
        "ds_read_b64_tr_b16 %0, %16 offset:0\n\t"
        "ds_read_b64_tr_b16 %1, %16 offset:512\n\t"
        "ds_read_b64_tr_b16 %2, %16 offset:1024\n\t"
        "ds_read_b64_tr_b16 %3, %16 offset:1536\n\t"
        "ds_read_b64_tr_b16 %4, %16 offset:2048\n\t"
        "ds_read_b64_tr_b16 %5, %16 offset:2560\n\t"
        "ds_read_b64_tr_b16 %6, %16 offset:3072\n\t"
        "ds_read_b64_tr_b16 %7, %16 offset:3584\n\t"
        "ds_read_b64_tr_b16 %8, %16 offset:4096\n\t"
        "ds_read_b64_tr_b16 %9, %16 offset:4608\n\t"
        "ds_read_b64_tr_b16 %10, %16 offset:5120\n\t"
        "ds_read_b64_tr_b16 %11, %16 offset:5632\n\t"
        "ds_read_b64_tr_b16 %12, %16 offset:6144\n\t"
        "ds_read_b64_tr_b16 %13, %16 offset:6656\n\t"
        "ds_read_b64_tr_b16 %14, %16 offset:7168\n\t"
        "ds_read_b64_tr_b16 %15, %16 offset:7680"
        : "=&v"(tv0), "=&v"(tv1), "=&v"(tv2), "=&v"(tv3),
          "=&v"(tv4), "=&v"(tv5), "=&v"(tv6), "=&v"(tv7),
          "=&v"(tv8), "=&v"(tv9), "=&v"(tva), "=&v"(tvb),
          "=&v"(tvc), "=&v"(tvd), "=&v"(tve), "=&v"(tvf)
        : "v"(va));

    // P = exp2(S) (max-free), packed as PV A-fragments (sigma order)
    bf16x8 pa[2][2];
#pragma unroll
    for (int m2 = 0; m2 < 2; ++m2)
#pragma unroll
      for (int kk = 0; kk < 2; ++kk) {
        f32x4 e0, e1;
#pragma unroll
        for (int r = 0; r < 4; ++r) {
          e0[r] = fast_exp2(sT[2 * kk][m2][r]);
          e1[r] = fast_exp2(sT[2 * kk + 1][m2][r]);
        }
        bf16x4 c0 = __builtin_convertvector(e0, bf16x4);
        bf16x4 c1 = __builtin_convertvector(e1, bf16x4);
        pa[m2][kk] = __builtin_shufflevector(c0, c1, 0, 1, 2, 3, 4, 5, 6, 7);
      }

    asm volatile("s_waitcnt lgkmcnt(0)" ::: "memory");
    __builtin_amdgcn_sched_barrier(0);

    bf16x8 vf[2][4];
    vf[0][0] = __builtin_shufflevector(tv0, tv1, 0, 1, 2, 3, 4, 5, 6, 7);
    vf[0][1] = __builtin_shufflevector(tv2, tv3, 0, 1, 2, 3, 4, 5, 6, 7);
    vf[0][2] = __builtin_shufflevector(tv4, tv5, 0, 1, 2, 3, 4, 5, 6, 7);
    vf[0][3] = __builtin_shufflevector(tv6, tv7, 0, 1, 2, 3, 4, 5, 6, 7);
    vf[1][0] = __builtin_shufflevector(tv8, tv9, 0, 1, 2, 3, 4, 5, 6, 7);
    vf[1][1] = __builtin_shufflevector(tva, tvb, 0, 1, 2, 3, 4, 5, 6, 7);
    vf[1][2] = __builtin_shufflevector(tvc, tvd, 0, 1, 2, 3, 4, 5, 6, 7);
    vf[1][3] = __builtin_shufflevector(tve, tvf, 0, 1, 2, 3, 4, 5, 6, 7);

    __builtin_amdgcn_s_setprio(1);
#pragma unroll
    for (int kk = 0; kk < 2; ++kk)
#pragma unroll
      for (int m2 = 0; m2 < 2; ++m2) {
#pragma unroll
        for (int nj = 0; nj < 4; ++nj)
          oacc[m2][nj] = __builtin_amdgcn_mfma_f32_16x16x32_bf16(pa[m2][kk], vf[kk][nj], oacc[m2][nj], 0, 0, 0);
        lacc[m2] = __builtin_amdgcn_mfma_f32_16x16x32_bf16(pa[m2][kk], onesf, lacc[m2], 0, 0, 0);
      }
    __builtin_amdgcn_s_setprio(0);
  };

  // prologue: tiles 0,1,2 staged (6 loads in flight)
  stage(0);
  stage(1);
  stage(2);
  int nxt = 3;
  // steady state i=0..13: entry outstanding = {2i,2i+1,2i+2} (6 loads)
  for (int i = 0; i < 14; ++i) {
    WAITV(4);            // tile 2i resident (all but newest 2 groups)
    SBAR();
    stage(nxt % 5); ++nxt;
    stage(nxt % 5); ++nxt;
    tile_compute((2 * i) % 5);
    WAITV(6);            // tile 2i+1 resident (newest 3 groups may remain)
    tile_compute((2 * i + 1) % 5);
  }
  // i=14: entry {28,29,30}; stage 31 only
  WAITV(4);
  SBAR();
  stage(31 % 5);
  tile_compute(28 % 5);
  WAITV(4);              // tile 29 resident (30,31 may remain)
  tile_compute(29 % 5);
  // i=15: entry {30,31}
  WAITV(2);
  SBAR();
  tile_compute(30 % 5);
  WAITV(0);
  tile_compute(31 % 5);

#pragma unroll
  for (int m2 = 0; m2 < 2; ++m2)
#pragma unroll
    for (int r = 0; r < 4; ++r) {
      float inv = 1.f / lacc[m2][r];
      long row = q0 + m2 * 16 + lg * 4 + r;
#pragma unroll
      for (int nj = 0; nj < 4; ++nj)
        og[hoff + row * 64 + nj * 16 + lr] = (bf16_t)(oacc[m2][nj][r] * inv);
    }
}

// ---------------------------------------------------------------- fused prologue
// One dispatch for ALL weight transposes + x cast.
// blocks [0,6144): 512x512 transposes (24 mats: L=z>>2, which=z&3)
// blocks [6144,12288): w1 (512,2048)->(2048,512) per layer
// blocks [12288,18432): w2 (2048,512)->(512,2048) per layer
// blocks [18432,22528): init_x elementwise cast
__global__ __launch_bounds__(256) void prologue_all(const float* __restrict__ wq,
                                                    const float* __restrict__ wk,
                                                    const float* __restrict__ wv,
                                                    const float* __restrict__ wo,
                                                    const float* __restrict__ w1,
                                                    const float* __restrict__ w2,
                                                    const float* __restrict__ x,
                                                    bf16_t* __restrict__ wqkvt,
                                                    bf16_t* __restrict__ wot,
                                                    bf16_t* __restrict__ w1t,
                                                    bf16_t* __restrict__ w2t,
                                                    bf16_t* __restrict__ xb) {
  const int b = blockIdx.x;
  const int t = threadIdx.x;
  if (b >= 18432) {  // init_x segment
    long i = ((long)(b - 18432) * 256 + t) * 8;
    f32x4 a = *(const f32x4*)(x + i);
    f32x4 c = *(const f32x4*)(x + i + 4);
    bf16x8 o;
#pragma unroll
    for (int j = 0; j < 4; ++j) { o[j] = (bf16_t)a[j]; o[4 + j] = (bf16_t)c[j]; }
    *(bf16x8*)(xb + i) = o;
    return;
  }
  __shared__ float tile[32][33];
  const float* src;
  bf16_t* dst;
  int K, N, n0, k0;
  float scale = 1.f;
  const long LQKV = 1536L * 512;
  if (b < 6144) {
    int z = b >> 8, rem = b & 255;
    int L = z >> 2, which = z & 3;
    K = 512; N = 512;
    n0 = (rem & 15) * 32;
    k0 = (rem >> 4) * 32;
    if (which == 0) { src = wq; dst = wqkvt + (long)L * LQKV; scale = QSCALE; }
    else if (which == 1) { src = wk; dst = wqkvt + (long)L * LQKV + 512 * 512; }
    else if (which == 2) { src = wv; dst = wqkvt + (long)L * LQKV + 2 * 512 * 512; }
    else { src = wo; dst = wot + (long)L * 512 * 512; }
    src += (long)L * 512 * 512;
  } else if (b < 12288) {
    int i = b - 6144;
    int z = i >> 10, rem = i & 1023;
    K = 512; N = 2048;
    n0 = (rem & 63) * 32;
    k0 = (rem >> 6) * 32;
    src = w1 + (long)z * 512 * 2048;
    dst = w1t + (long)z * 2048 * 512;
  } else {
    int i = b - 12288;
    int z = i >> 10, rem = i & 1023;
    K = 2048; N = 512;
    n0 = (rem & 15) * 32;
    k0 = (rem >> 4) * 32;
    src = w2 + (long)z * 2048 * 512;
    dst = w2t + (long)z * 512 * 2048;
  }
  const int tx = t & 31, ty = t >> 5;
#pragma unroll
  for (int i = 0; i < 4; ++i)
    tile[ty + i * 8][tx] = src[(long)(k0 + ty + i * 8) * N + n0 + tx];
  __syncthreads();
#pragma unroll
  for (int i = 0; i < 4; ++i)
    dst[(long)(n0 + ty + i * 8) * K + k0 + tx] = (bf16_t)(tile[tx][ty + i * 8] * scale);
}

// ---------------------------------------------------------------- launch
extern "C" void kernel_launch(void* const* d_in, const int* in_sizes, int n_in,
                              void* d_out, int out_size, void* d_ws, size_t ws_size,
                              hipStream_t stream) {
  const float* x = (const float*)d_in[0];
  const float* wq = (const float*)d_in[1];
  const float* wk = (const float*)d_in[2];
  const float* wv = (const float*)d_in[3];
  const float* wo = (const float*)d_in[4];
  const float* w1 = (const float*)d_in[5];
  const float* b1 = (const float*)d_in[6];
  const float* w2 = (const float*)d_in[7];
  const float* b2 = (const float*)d_in[8];
  const float* g1 = (const float*)d_in[9];
  const float* be1 = (const float*)d_in[10];
  const float* g2 = (const float*)d_in[11];
  const float* be2 = (const float*)d_in[12];

  char* ws = (char*)d_ws;

  const int M = 16384, D = 512, DFF = 2048, NL = 6;
  const size_t sz_small = (size_t)NL * D * D * 2;
  const size_t sz_big = (size_t)NL * D * DFF * 2;
  bf16_t* wqkvt = (bf16_t*)(ws);                       // [NL][1536][512]
  bf16_t* wot = (bf16_t*)(ws + 3 * sz_small);
  bf16_t* w1t = (bf16_t*)(ws + 4 * sz_small);
  bf16_t* w2t = (bf16_t*)(ws + 4 * sz_small + sz_big);
  char* actbase = ws + 4 * sz_small + 2 * sz_big;
  bf16_t* xb = (bf16_t*)(actbase);                         // bf16 residual master
  char* R = actbase + (size_t)M * D * 2;
  bf16_t* qb = (bf16_t*)(R);
  bf16_t* kb = (bf16_t*)(R + (size_t)M * D * 2);
  bf16_t* vb = (bf16_t*)(R + 2 * (size_t)M * D * 2);
  bf16_t* ob = (bf16_t*)(R + 3 * (size_t)M * D * 2);
  bf16_t* hb = (bf16_t*)(R);                               // FFN hidden reuses R

  const long LQKV = 1536L * 512;
  prologue_all<<<dim3(22528), 256, 0, stream>>>(wq, wk, wv, wo, w1, w2, x,
                                                wqkvt, wot, w1t, w2t, xb);

  for (int L = 0; L < NL; ++L) {
    const bf16_t* wqkvL = wqkvt + (size_t)L * LQKV;
    const bf16_t* w1L = w1t + (size_t)L * D * DFF;
    const bf16_t* w2L = w2t + (size_t)L * D * DFF;
    const bf16_t* woL = wot + (size_t)L * D * D;

    gemm_bt<0, 0, 1, 0><<<dim3(12, 128), 256, 0, stream>>>(xb, wqkvL, nullptr, qb, M, 1536, D, 512);
    attn_fa<<<dim3(512), 512, 0, stream>>>(qb, kb, vb, ob);
    gemm_resln<0, 0><<<dim3(256), 512, 0, stream>>>(ob, woL, nullptr, xb, nullptr,
                                                    g1 + L * D, be1 + L * D, D);
    gemm_bt<1, 1, 0, 0><<<dim3(16, 128), 256, 0, stream>>>(xb, w1L, b1 + (size_t)L * DFF, hb, M, DFF, D, DFF);
    if (L == NL - 1)
      gemm_resln<1, 1><<<dim3(256), 512, 0, stream>>>(hb, w2L, b2 + L * D, xb, (float*)d_out,
                                                      g2 + L * D, be2 + L * D, DFF);
    else
      gemm_resln<1, 0><<<dim3(256), 512, 0, stream>>>(hb, w2L, b2 + L * D, xb, nullptr,
                                                      g2 + L * D, be2 + L * D, DFF);
  }
}